// Round 4
// baseline (210.562 us; speedup 1.0000x reference)
//
#include <hip/hip_runtime.h>

#define B_ 8
#define T_ 2048
#define H_ 256
#define BR 64
#define BC 64
#define NKV 2              // kv-range splits (partials combined via atomicAdd; valid because no-max softmax)
#define KSTR 264           // K LDS row stride: 132 dw == 4 mod 32 -> 8x4-bank groups, 2-way max
#define VSTR 72            // 36 dw == 4 mod 32
#define PSTR 72
#define SCALE2 0.0901684403f     // (1/16) * log2(e)
#define SLOPE2 0.00563552752f    // 2^-8 * log2(e)

typedef __attribute__((ext_vector_type(8))) short bf16x8;
typedef __attribute__((ext_vector_type(4))) float f32x4;

#define MFMA16(a, b, c) __builtin_amdgcn_mfma_f32_16x16x32_bf16((a), (b), (c), 0, 0, 0)

__device__ __forceinline__ ushort f2bf(float f) {
  unsigned u = __float_as_uint(f);
  u += 0x7FFFu + ((u >> 16) & 1u);   // RNE; finite inputs
  return (ushort)(u >> 16);
}

// ---- fused prologue: blocks [0,512) RoPE(q,k)->bf16; [512,1536) v transpose ----
__global__ void prep_kernel(const float* __restrict__ q, const float* __restrict__ k,
                            const float* __restrict__ v,
                            ushort* __restrict__ qe, ushort* __restrict__ ke,
                            ushort* __restrict__ vt) {
  __shared__ ushort tile[64][72];
  const int bid = blockIdx.x;
  const int tid = threadIdx.x;
  if (bid < 512) {
    int idx = bid * 256 + tid;          // 0 .. T*64-1
    int jp = idx & 63, t = idx >> 6;
    int j = jp * 2;
    float f0 = exp2f((float)j * -0.103810252959f);       // -log2(10000)/128
    float f1 = exp2f((float)(j + 1) * -0.103810252959f);
    // fast sin/cos: reduce to [0,2pi) via revolutions, then HW sin/cos
    float rv0 = (float)t * f0 * 0.15915494309f;
    float rv1 = (float)t * f1 * 0.15915494309f;
    float red0 = (rv0 - floorf(rv0)) * 6.28318530718f;
    float red1 = (rv1 - floorf(rv1)) * 6.28318530718f;
    float sn0 = __sinf(red0), cs0 = __cosf(red0);
    float sn1 = __sinf(red1), cs1 = __cosf(red1);
    for (int b = 0; b < B_; ++b) {
      size_t base = ((size_t)(b * T_ + t)) * H_ + j;
      float2 a = *(const float2*)(q + base);
      float2 c = *(const float2*)(q + base + 128);
      ushort2 lo, hi;
      lo.x = f2bf(a.x * cs0 - c.x * sn0); lo.y = f2bf(a.y * cs1 - c.y * sn1);
      hi.x = f2bf(c.x * cs0 + a.x * sn0); hi.y = f2bf(c.y * cs1 + a.y * sn1);
      *(ushort2*)(qe + base) = lo; *(ushort2*)(qe + base + 128) = hi;
      a = *(const float2*)(k + base);
      c = *(const float2*)(k + base + 128);
      lo.x = f2bf(a.x * cs0 - c.x * sn0); lo.y = f2bf(a.y * cs1 - c.y * sn1);
      hi.x = f2bf(c.x * cs0 + a.x * sn0); hi.y = f2bf(c.y * cs1 + a.y * sn1);
      *(ushort2*)(ke + base) = lo; *(ushort2*)(ke + base + 128) = hi;
    }
  } else {
    // V transpose: v[B,T,H] fp32 -> vt[B,H,T] bf16, 64x64 tiles.
    // XOR-8 column swizzle keyed on row>>3: write phase wave-uniform (free),
    // read phase becomes conflict-free (was 16-way).
    int bid2 = bid - 512;
    int b = bid2 >> 7, rem = bid2 & 127;
    int h0 = (rem >> 5) * 64, t0 = (rem & 31) * 64;
    int c4 = tid & 15, r0 = tid >> 4;
#pragma unroll
    for (int p = 0; p < 4; ++p) {
      int row = r0 + p * 16;
      const float4 f = *(const float4*)(v + ((size_t)(b * T_ + t0 + row)) * H_ + h0 + c4 * 4);
      ushort4 u;
      u.x = f2bf(f.x); u.y = f2bf(f.y); u.z = f2bf(f.z); u.w = f2bf(f.w);
      *(ushort4*)&tile[row][(c4 * 4) ^ (8 * ((row >> 3) & 7))] = u;
    }
    __syncthreads();
#pragma unroll
    for (int p = 0; p < 2; ++p) {
      int c = tid + p * 256;
      int h = c >> 3, tc = (c & 7) * 8;
      int xo = 8 * (c & 7);          // (tc+i)>>3 == c&7 for i<8
      ushort4 u0, u1;
      u0.x = tile[tc + 0][h ^ xo]; u0.y = tile[tc + 1][h ^ xo];
      u0.z = tile[tc + 2][h ^ xo]; u0.w = tile[tc + 3][h ^ xo];
      u1.x = tile[tc + 4][h ^ xo]; u1.y = tile[tc + 5][h ^ xo];
      u1.z = tile[tc + 6][h ^ xo]; u1.w = tile[tc + 7][h ^ xo];
      ushort* dst = vt + ((size_t)(b * H_ + h0 + h)) * T_ + t0 + tc;
      *(ushort4*)dst = u0;
      *(ushort4*)(dst + 4) = u1;
    }
  }
}

// ---- Flash attention, no-max softmax, kv-split partials into out/lsum via atomicAdd ----
// 8 waves: w -> mh=w>>2 (32-row half), cw=w&3 (16-col slice of S / 64-h slice of O).
__global__ __launch_bounds__(512, 4)
void attn_kernel(const ushort* __restrict__ qe, const ushort* __restrict__ ke,
                 const ushort* __restrict__ vT, float* __restrict__ out,
                 float* __restrict__ lsum) {
  __shared__ ushort Ksh[BC * KSTR];     // 33792 B
  __shared__ ushort Vsh[H_ * VSTR];     // 36864 B (shared [h][kv])
  __shared__ ushort Psh[BR * PSTR];     // 9216 B   -> total 79872 B, 2 blocks/CU

  const int tid = threadIdx.x;
  const int w = tid >> 6, lane = tid & 63, quad = lane >> 4, l16 = lane & 15;
  const int mh = w >> 2, cw = w & 3;
  const int b = blockIdx.z, sp = blockIdx.y;
  const int q0 = blockIdx.x * BR;
  const int kvbase = sp * (T_ / NKV);

  // Q A-fragments in registers (rows 32*mh + mt*16 + l16)
  bf16x8 aq[2][8];
  const ushort* qbase = qe + (size_t)(b * T_ + q0 + 32 * mh) * H_;
#pragma unroll
  for (int mt = 0; mt < 2; ++mt)
#pragma unroll
    for (int ks = 0; ks < 8; ++ks)
      aq[mt][ks] = *(const bf16x8*)(qbase + (size_t)(mt * 16 + l16) * H_ + ks * 32 + quad * 8);

  const f32x4 fzero = {0.f, 0.f, 0.f, 0.f};
  f32x4 O[2][4], lac[2];
#pragma unroll
  for (int mt = 0; mt < 2; ++mt) {
    lac[mt] = fzero;
#pragma unroll
    for (int ht = 0; ht < 4; ++ht) O[mt][ht] = fzero;
  }
  bf16x8 vones;
#pragma unroll
  for (int i = 0; i < 8; ++i) vones[i] = (short)0x3F80;   // bf16 1.0

  // staging addresses (512 threads)
  const ushort* ksrc = ke + (size_t)(b * T_ + kvbase + (tid >> 5)) * H_ + (tid & 31) * 8;
  const int kdst = (tid >> 5) * KSTR + (tid & 31) * 8;
  const ushort* vsrc = vT + (size_t)(b * H_ + (tid >> 3)) * T_ + kvbase + (tid & 7) * 8;
  const int vdst = (tid >> 3) * VSTR + (tid & 7) * 8;

  const float ar0 = SLOPE2 * (float)(q0 + 32 * mh + quad * 4);

  for (int it = 0; it < T_ / NKV / BC; ++it) {     // 16 iters
    const int kv0 = kvbase + it * BC;
    __syncthreads();   // prev iter's Ksh/Vsh/Psh readers done
#pragma unroll
    for (int i = 0; i < 4; ++i)
      *(uint4*)&Ksh[kdst + i * (16 * KSTR)] = *(const uint4*)(ksrc + (size_t)it * BC * H_ + (size_t)i * 16 * H_);
#pragma unroll
    for (int i = 0; i < 4; ++i)
      *(uint4*)&Vsh[vdst + i * (64 * VSTR)] = *(const uint4*)(vsrc + (size_t)it * BC + (size_t)i * 64 * T_);
    __syncthreads();

    // QK^T: S rows [32mh,32mh+32), cols [16cw,16cw+16)
    f32x4 s0 = fzero, s1 = fzero;
    const int krow = (16 * cw + l16) * KSTR + quad * 8;
#pragma unroll
    for (int kk = 0; kk < 8; ++kk) {
      bf16x8 bk = *(const bf16x8*)&Ksh[krow + kk * 32];
      s0 = MFMA16(aq[0][kk], bk, s0);
      s1 = MFMA16(aq[1][kk], bk, s1);
    }
    // p = exp2(s*SCALE2 + SLOPE2*(col - row)) -> bf16 Psh
    const float ac = SLOPE2 * (float)(kv0 + 16 * cw + l16);
#pragma unroll
    for (int r = 0; r < 4; ++r) {
      float a0 = ac - ar0 - SLOPE2 * (float)r;
      float p0 = __builtin_amdgcn_exp2f(fmaf(s0[r], SCALE2, a0));
      float p1 = __builtin_amdgcn_exp2f(fmaf(s1[r], SCALE2, a0 - SLOPE2 * 16.0f));
      Psh[(32 * mh + quad * 4 + r) * PSTR + 16 * cw + l16] = f2bf(p0);
      Psh[(32 * mh + 16 + quad * 4 + r) * PSTR + 16 * cw + l16] = f2bf(p1);
    }
    __syncthreads();   // P complete

    // PV + rowsum(P) via ones-MFMA; wave: m rows 32mh+, h slice [64cw, 64cw+64)
#pragma unroll
    for (int s2 = 0; s2 < 2; ++s2) {
      bf16x8 a0 = *(const bf16x8*)&Psh[(32 * mh + l16) * PSTR + s2 * 32 + quad * 8];
      bf16x8 a1 = *(const bf16x8*)&Psh[(32 * mh + 16 + l16) * PSTR + s2 * 32 + quad * 8];
      lac[0] = MFMA16(a0, vones, lac[0]);
      lac[1] = MFMA16(a1, vones, lac[1]);
#pragma unroll
      for (int ht = 0; ht < 4; ++ht) {
        bf16x8 bv = *(const bf16x8*)&Vsh[(64 * cw + ht * 16 + l16) * VSTR + s2 * 32 + quad * 8];
        O[0][ht] = MFMA16(a0, bv, O[0][ht]);
        O[1][ht] = MFMA16(a1, bv, O[1][ht]);
      }
    }
  }

  // epilogue: accumulate unnormalized partials (out zeroed by host memset)
  float* obase = out + (size_t)(b * T_ + q0 + 32 * mh) * H_ + 64 * cw;
#pragma unroll
  for (int mt = 0; mt < 2; ++mt)
#pragma unroll
    for (int r = 0; r < 4; ++r) {
      int row = mt * 16 + quad * 4 + r;
#pragma unroll
      for (int ht = 0; ht < 4; ++ht)
        atomicAdd(&obase[(size_t)row * H_ + ht * 16 + l16], O[mt][ht][r]);
    }
  if (cw == 0 && l16 == 0) {   // lac identical across cw; one writer per row
#pragma unroll
    for (int mt = 0; mt < 2; ++mt)
#pragma unroll
      for (int r = 0; r < 4; ++r)
        atomicAdd(&lsum[b * T_ + q0 + 32 * mh + mt * 16 + quad * 4 + r], lac[mt][r]);
  }
}

// ---- normalize: out[b,t,:] /= lsum[b,t] ----
__global__ void norm_kernel(float* __restrict__ out, const float* __restrict__ lsum) {
  int idx = blockIdx.x * 256 + threadIdx.x;   // over B*T*H/4
  float inv = 1.0f / lsum[idx >> 6];          // H/4 = 64 float4 per row
  float4* p = (float4*)out + idx;
  float4 v = *p;
  v.x *= inv; v.y *= inv; v.z *= inv; v.w *= inv;
  *p = v;
}

extern "C" void kernel_launch(void* const* d_in, const int* in_sizes, int n_in,
                              void* d_out, int out_size, void* d_ws, size_t ws_size,
                              hipStream_t stream) {
  const float* q = (const float*)d_in[0];
  const float* k = (const float*)d_in[1];
  const float* v = (const float*)d_in[2];
  float* out = (float*)d_out;

  const size_t elems = (size_t)B_ * T_ * H_;
  ushort* qe = (ushort*)d_ws;
  ushort* ke = qe + elems;
  ushort* vt = ke + elems;
  float* lsum = (float*)(vt + elems);   // B*T floats

  hipMemsetAsync(out, 0, elems * sizeof(float), stream);
  hipMemsetAsync(lsum, 0, (size_t)B_ * T_ * sizeof(float), stream);
  prep_kernel<<<dim3(1536), 256, 0, stream>>>(q, k, v, qe, ke, vt);
  attn_kernel<<<dim3(T_ / BR, NKV, B_), 512, 0, stream>>>(qe, ke, vt, out, lsum);
  norm_kernel<<<dim3((B_ * T_ * H_ / 4) / 256), 256, 0, stream>>>(out, lsum);
}